// Round 7
// baseline (541.230 us; speedup 1.0000x reference)
//
#include <hip/hip_runtime.h>

typedef __attribute__((ext_vector_type(4))) float f32x4;
typedef __attribute__((ext_vector_type(16))) float f32x16;
typedef __attribute__((ext_vector_type(4))) unsigned short u16x4;
typedef __attribute__((ext_vector_type(4))) int i32x4;
typedef __attribute__((ext_vector_type(8))) __bf16 bf16x8;

union FragAB {
  u16x4 u[2];
  i32x4 v;
  bf16x8 f;
};

static __device__ __forceinline__ unsigned short f2bf(float x) {
  union { float f; unsigned u; } v;
  v.f = x;
  unsigned r = v.u + 0x7FFFu + ((v.u >> 16) & 1u);  // round-to-nearest-even
  return (unsigned short)(r >> 16);
}

#define NN 8192

// ---------- kernel 1: d_out = bias (broadcast) ----------
__global__ __launch_bounds__(256) void k_bias(const float* __restrict__ bias,
                                              float* __restrict__ out) {
  out[(size_t)blockIdx.x * 256 + threadIdx.x] = bias[threadIdx.x];
}

// ---------- kernel 2: Bp = (V @ [w1|w2|w3-w1-w2])^T, k-blocked bf16 --------
// Bp element (ty, n, j) at  ty*2097152 + (j>>4)*4096 + n*16 + (j&15).
// ty=2 plane holds H12 = V@(w3-w1-w2) directly (bit-plane decomposition),
// so no separate fix-up kernel is needed.
__global__ __launch_bounds__(256) void k_transform(
    const float* __restrict__ V, const float* __restrict__ w1,
    const float* __restrict__ w2, const float* __restrict__ w3,
    unsigned short* __restrict__ Bp) {
  int bx = blockIdx.x;
  int rb = bx & 63;   // j tile of 128
  int nb = bx >> 6;   // 0..11 (64-wide col tile within 768)
  int nc0 = (nb & 3) * 64;
  int tid = threadIdx.x;
  int lane = tid & 63;
  int wv = tid >> 6;
  int wm = wv >> 1, wn = wv & 1;
  int q = lane >> 4, l16 = lane & 15;

  __shared__ unsigned short tA[128][36];
  __shared__ unsigned short tB[64][36];

  f32x4 acc[4][2];
#pragma unroll
  for (int i = 0; i < 4; i++)
#pragma unroll
    for (int j = 0; j < 2; j++) acc[i][j] = (f32x4)0.0f;

  for (int kk = 0; kk < 256; kk += 32) {
    {
      int r = tid >> 1, c0 = (tid & 1) * 16;
      const float* src = V + (size_t)(rb * 128 + r) * 256 + kk + c0;
      f32x4 f0 = *(const f32x4*)(src + 0);
      f32x4 f1 = *(const f32x4*)(src + 4);
      f32x4 f2 = *(const f32x4*)(src + 8);
      f32x4 f3 = *(const f32x4*)(src + 12);
      unsigned short* d = &tA[r][c0];
      d[0] = f2bf(f0.x);  d[1] = f2bf(f0.y);  d[2] = f2bf(f0.z);  d[3] = f2bf(f0.w);
      d[4] = f2bf(f1.x);  d[5] = f2bf(f1.y);  d[6] = f2bf(f1.z);  d[7] = f2bf(f1.w);
      d[8] = f2bf(f2.x);  d[9] = f2bf(f2.y);  d[10] = f2bf(f2.z); d[11] = f2bf(f2.w);
      d[12] = f2bf(f3.x); d[13] = f2bf(f3.y); d[14] = f2bf(f3.z); d[15] = f2bf(f3.w);
    }
    {
      int r = tid >> 3, cg = (tid & 7) * 8;
      size_t off = (size_t)(kk + r) * 256 + nc0 + cg;
      f32x4 g0, g1;
      if (nb < 4) {
        g0 = *(const f32x4*)(w1 + off);
        g1 = *(const f32x4*)(w1 + off + 4);
      } else if (nb < 8) {
        g0 = *(const f32x4*)(w2 + off);
        g1 = *(const f32x4*)(w2 + off + 4);
      } else {
        f32x4 a0 = *(const f32x4*)(w1 + off), a1 = *(const f32x4*)(w1 + off + 4);
        f32x4 b0 = *(const f32x4*)(w2 + off), b1 = *(const f32x4*)(w2 + off + 4);
        f32x4 d0 = *(const f32x4*)(w3 + off), d1 = *(const f32x4*)(w3 + off + 4);
        g0 = d0 - a0 - b0;
        g1 = d1 - a1 - b1;
      }
      tB[cg + 0][r] = f2bf(g0.x); tB[cg + 1][r] = f2bf(g0.y);
      tB[cg + 2][r] = f2bf(g0.z); tB[cg + 3][r] = f2bf(g0.w);
      tB[cg + 4][r] = f2bf(g1.x); tB[cg + 5][r] = f2bf(g1.y);
      tB[cg + 6][r] = f2bf(g1.z); tB[cg + 7][r] = f2bf(g1.w);
    }
    __syncthreads();
    FragAB af[4], bf[2];
#pragma unroll
    for (int mt = 0; mt < 4; mt++) {
      const unsigned short* p = &tA[wm * 64 + mt * 16 + l16][q * 8];
      af[mt].u[0] = *(const u16x4*)p;
      af[mt].u[1] = *(const u16x4*)(p + 4);
    }
#pragma unroll
    for (int nt = 0; nt < 2; nt++) {
      const unsigned short* p = &tB[wn * 32 + nt * 16 + l16][q * 8];
      bf[nt].u[0] = *(const u16x4*)p;
      bf[nt].u[1] = *(const u16x4*)(p + 4);
    }
#pragma unroll
    for (int mt = 0; mt < 4; mt++)
#pragma unroll
      for (int nt = 0; nt < 2; nt++)
        acc[mt][nt] = __builtin_amdgcn_mfma_f32_16x16x32_bf16(
            af[mt].f, bf[nt].f, acc[mt][nt], 0, 0, 0);
    __syncthreads();
  }
  int ty = nb >> 2;
#pragma unroll
  for (int mt = 0; mt < 4; mt++)
#pragma unroll
    for (int nt = 0; nt < 2; nt++) {
      int n = (nb & 3) * 64 + wn * 32 + nt * 16 + l16;
      int j0 = rb * 128 + wm * 64 + mt * 16 + q * 4;
      u16x4 hv;
      hv.x = f2bf(acc[mt][nt].x);
      hv.y = f2bf(acc[mt][nt].y);
      hv.z = f2bf(acc[mt][nt].z);
      hv.w = f2bf(acc[mt][nt].w);
      size_t idx = (size_t)ty * 2097152 + (size_t)(j0 >> 4) * 4096 + n * 16 + (j0 & 15);
      *(u16x4*)(Bp + idx) = hv;
    }
}

// ---------- kernel 2c: pack adj into 2-bit planes ----------
// P[(ks*32+s)*2 + q][row] (u32, row fastest): bits[2j..] = adj octet kh=0,
// bits[16+2j..] = octet kh=1. v2: 2048 blocks x 32 rows, prefetched pass loop.
__global__ __launch_bounds__(256) void k_pack(const int* __restrict__ adj,
                                              unsigned* __restrict__ P) {
  int bx = blockIdx.x;
  int rowblk = bx >> 3, ks = bx & 7;
  int t = threadIdx.x;
  int r0 = rowblk * 32;
  __shared__ unsigned hal[32][129];  // 16-bit octet codes, padded

  // phase 1: 16 passes; each pass 2 rows x 128 octets; prefetch next pass
  int rl = t >> 7;   // 0/1
  int o = t & 127;
  const int* src0 = adj + (size_t)(r0 + rl) * NN + ks * 1024 + o * 8;
  i32x4 v0 = *(const i32x4*)src0;
  i32x4 v1 = *(const i32x4*)(src0 + 4);
  for (int p = 0; p < 16; p++) {
    i32x4 u0 = v0, u1 = v1;
    if (p < 15) {
      const int* s = src0 + (size_t)(p + 1) * 2 * NN;
      v0 = *(const i32x4*)s;
      v1 = *(const i32x4*)(s + 4);
    }
    unsigned b = (unsigned)(u0.x & 3) | ((unsigned)(u0.y & 3) << 2) |
                 ((unsigned)(u0.z & 3) << 4) | ((unsigned)(u0.w & 3) << 6) |
                 ((unsigned)(u1.x & 3) << 8) | ((unsigned)(u1.y & 3) << 10) |
                 ((unsigned)(u1.z & 3) << 12) | ((unsigned)(u1.w & 3) << 14);
    hal[p * 2 + rl][o] = b;
  }
  __syncthreads();
  // phase 2: 2048 u32 out; lanes sweep row -> 128B contiguous segments
  for (int i = 0; i < 8; i++) {
    int oi = i * 256 + t;
    int row = oi & 31, sq = oi >> 5;  // sq = s*2+q, 0..63
    int s = sq >> 1, q = sq & 1;
    unsigned lo = hal[row][s * 4 + q];
    unsigned hi = hal[row][s * 4 + 2 + q];
    P[((size_t)(ks * 32 + s) * 2 + q) * 8192 + r0 + row] = lo | (hi << 16);
  }
}

// expand 16 bits (8 x 2-bit adj) into bit-plane masks (bf16 one-hot)
static __device__ __forceinline__ void expand2(unsigned bits, FragAB& fA,
                                               FragAB& fB) {
  unsigned short a[8], b[8];
#pragma unroll
  for (int e = 0; e < 8; e++) {
    a[e] = (bits & (1u << (2 * e))) ? 0x3F80 : 0;
    b[e] = (bits & (2u << (2 * e))) ? 0x3F80 : 0;
  }
  fA.u[0] = u16x4{a[0], a[1], a[2], a[3]};
  fA.u[1] = u16x4{a[4], a[5], a[6], a[7]};
  fB.u[0] = u16x4{b[0], b[1], b[2], b[3]};
  fB.u[1] = u16x4{b[4], b[5], b[6], b[7]};
}

// ---------- kernel 3: out += b0@H1 + b1@H2 + (b0&b1)@H12 ----------
// v7: BM=128 (halves B re-read to 0.8 GB), BN=256, BK=32, splitK=8
// -> 512 blocks (2/CU, 8 waves/CU). 4 waves, wave = 128rows x 64cols.
// NO LDS / barriers. A-side: 4 coalesced u32 P loads/step (prefetched),
// masks expanded in regs (fC = fA & fB), B direct from global
// (1KB/wave contiguous, XCD-L2-resident via ks=bx&7).
__global__ __launch_bounds__(256, 2) void k_agg(const unsigned* __restrict__ P,
                                                const unsigned short* __restrict__ Bp,
                                                float* __restrict__ out) {
  int bx = blockIdx.x;
  int ks = bx & 7, rb = bx >> 3;
  int tid = threadIdx.x, lane = tid & 63;
  int wv = tid >> 6;  // 0..3 = 64-col n-slab
  int q = lane >> 5, l32 = lane & 31;

  f32x16 acc[4][2];
#pragma unroll
  for (int mt = 0; mt < 4; mt++) {
    acc[mt][0] = (f32x16)0.0f;
    acc[mt][1] = (f32x16)0.0f;
  }

  // packed-adj pointer: plane (ks*32+s)*2+q, row rb*128 + mt*32 + l32
  const unsigned* pp = P + ((size_t)ks * 64 + q) * 8192 + rb * 128 + l32;

  // B pointers: n = wv*64 + nt*32 + l32; k-slice base ks*262144
  const unsigned short* bb[3][2];
#pragma unroll
  for (int ty = 0; ty < 3; ty++)
#pragma unroll
    for (int nt = 0; nt < 2; nt++) {
      int n = wv * 64 + nt * 32 + l32;
      bb[ty][nt] = Bp + (size_t)ty * 2097152 + (size_t)ks * 262144 + n * 16 + q * 8;
    }

  unsigned pk[4], npk[4];
#pragma unroll
  for (int mt = 0; mt < 4; mt++) pk[mt] = pp[mt * 32];

  for (int s = 0; s < 32; s++) {
    // batch-issue 12 B loads (coalesced 1KB/wave, XCD-L2-resident)
    FragAB bv[2][3][2];
    size_t soff = (size_t)s * 8192;
#pragma unroll
    for (int kh = 0; kh < 2; kh++)
#pragma unroll
      for (int ty = 0; ty < 3; ty++)
#pragma unroll
        for (int nt = 0; nt < 2; nt++)
          bv[kh][ty][nt].v = *(const i32x4*)(bb[ty][nt] + soff + kh * 4096);
    // prefetch next step's packed adj (4 coalesced u32 loads)
    if (s < 31) {
#pragma unroll
      for (int mt = 0; mt < 4; mt++)
        npk[mt] = pp[(size_t)(s + 1) * 16384 + mt * 32];
    }
    // expand + 48 MFMAs
#pragma unroll
    for (int mt = 0; mt < 4; mt++) {
#pragma unroll
      for (int kh = 0; kh < 2; kh++) {
        unsigned bits = (pk[mt] >> (kh * 16)) & 0xFFFFu;
        FragAB fA, fB, fC;
        expand2(bits, fA, fB);
        fC.v = fA.v & fB.v;  // adj==3
        acc[mt][0] = __builtin_amdgcn_mfma_f32_32x32x16_bf16(
            fA.f, bv[kh][0][0].f, acc[mt][0], 0, 0, 0);
        acc[mt][1] = __builtin_amdgcn_mfma_f32_32x32x16_bf16(
            fA.f, bv[kh][0][1].f, acc[mt][1], 0, 0, 0);
        acc[mt][0] = __builtin_amdgcn_mfma_f32_32x32x16_bf16(
            fB.f, bv[kh][1][0].f, acc[mt][0], 0, 0, 0);
        acc[mt][1] = __builtin_amdgcn_mfma_f32_32x32x16_bf16(
            fB.f, bv[kh][1][1].f, acc[mt][1], 0, 0, 0);
        acc[mt][0] = __builtin_amdgcn_mfma_f32_32x32x16_bf16(
            fC.f, bv[kh][2][0].f, acc[mt][0], 0, 0, 0);
        acc[mt][1] = __builtin_amdgcn_mfma_f32_32x32x16_bf16(
            fC.f, bv[kh][2][1].f, acc[mt][1], 0, 0, 0);
      }
    }
#pragma unroll
    for (int mt = 0; mt < 4; mt++) pk[mt] = npk[mt];
  }

  // epilogue: C/D 32x32 layout col=lane&31, row=(reg&3)+8*(reg>>2)+4*q
#pragma unroll
  for (int mt = 0; mt < 4; mt++)
#pragma unroll
    for (int nt = 0; nt < 2; nt++) {
      int colbase = wv * 64 + nt * 32 + l32;
      int rowb = rb * 128 + mt * 32 + 4 * q;
#pragma unroll
      for (int r = 0; r < 16; r++) {
        int row = rowb + (r & 3) + 8 * (r >> 2);
        atomicAdd(out + (size_t)row * 256 + colbase, acc[mt][nt][r]);
      }
    }
}

extern "C" void kernel_launch(void* const* d_in, const int* in_sizes, int n_in,
                              void* d_out, int out_size, void* d_ws,
                              size_t ws_size, hipStream_t stream) {
  const float* V = (const float*)d_in[0];
  const int* adj = (const int*)d_in[1];
  const float* w1 = (const float*)d_in[2];
  const float* w2 = (const float*)d_in[3];
  const float* w3 = (const float*)d_in[4];
  const float* bias = (const float*)d_in[5];
  float* out = (float*)d_out;
  unsigned short* Bp = (unsigned short*)d_ws;            // 12.58 MB
  unsigned* P = (unsigned*)((char*)d_ws + 12582912);     // +16.78 MB

  k_bias<<<dim3(NN), dim3(256), 0, stream>>>(bias, out);
  k_pack<<<dim3(2048), dim3(256), 0, stream>>>(adj, P);
  k_transform<<<dim3(768), dim3(256), 0, stream>>>(V, w1, w2, w3, Bp);
  k_agg<<<dim3(512), dim3(256), 0, stream>>>(P, Bp, out);
}

// Round 8
// 505.302 us; speedup vs baseline: 1.0711x; 1.0711x over previous
//
#include <hip/hip_runtime.h>

typedef __attribute__((ext_vector_type(4))) float f32x4;
typedef __attribute__((ext_vector_type(16))) float f32x16;
typedef __attribute__((ext_vector_type(4))) unsigned short u16x4;
typedef __attribute__((ext_vector_type(4))) int i32x4;
typedef __attribute__((ext_vector_type(8))) __bf16 bf16x8;

union FragAB {
  u16x4 u[2];
  i32x4 v;
  bf16x8 f;
};

static __device__ __forceinline__ unsigned short f2bf(float x) {
  union { float f; unsigned u; } v;
  v.f = x;
  unsigned r = v.u + 0x7FFFu + ((v.u >> 16) & 1u);  // round-to-nearest-even
  return (unsigned short)(r >> 16);
}

#define NN 8192

// ---------- kernel 1: d_out = bias (broadcast) ----------
__global__ __launch_bounds__(256) void k_bias(const float* __restrict__ bias,
                                              float* __restrict__ out) {
  out[(size_t)blockIdx.x * 256 + threadIdx.x] = bias[threadIdx.x];
}

// ---------- kernel 2: Bp = (V @ [w1|w2|w3-w1-w2])^T, k-blocked bf16 --------
// Bp element (ty, n, j) at  ty*2097152 + (j>>4)*4096 + n*16 + (j&15).
// ty=2 plane holds H12 = V@(w3-w1-w2) (bit-plane decomposition).
__global__ __launch_bounds__(256) void k_transform(
    const float* __restrict__ V, const float* __restrict__ w1,
    const float* __restrict__ w2, const float* __restrict__ w3,
    unsigned short* __restrict__ Bp) {
  int bx = blockIdx.x;
  int rb = bx & 63;   // j tile of 128
  int nb = bx >> 6;   // 0..11 (64-wide col tile within 768)
  int nc0 = (nb & 3) * 64;
  int tid = threadIdx.x;
  int lane = tid & 63;
  int wv = tid >> 6;
  int wm = wv >> 1, wn = wv & 1;
  int q = lane >> 4, l16 = lane & 15;

  __shared__ unsigned short tA[128][36];
  __shared__ unsigned short tB[64][36];

  f32x4 acc[4][2];
#pragma unroll
  for (int i = 0; i < 4; i++)
#pragma unroll
    for (int j = 0; j < 2; j++) acc[i][j] = (f32x4)0.0f;

  for (int kk = 0; kk < 256; kk += 32) {
    {
      int r = tid >> 1, c0 = (tid & 1) * 16;
      const float* src = V + (size_t)(rb * 128 + r) * 256 + kk + c0;
      f32x4 f0 = *(const f32x4*)(src + 0);
      f32x4 f1 = *(const f32x4*)(src + 4);
      f32x4 f2 = *(const f32x4*)(src + 8);
      f32x4 f3 = *(const f32x4*)(src + 12);
      unsigned short* d = &tA[r][c0];
      d[0] = f2bf(f0.x);  d[1] = f2bf(f0.y);  d[2] = f2bf(f0.z);  d[3] = f2bf(f0.w);
      d[4] = f2bf(f1.x);  d[5] = f2bf(f1.y);  d[6] = f2bf(f1.z);  d[7] = f2bf(f1.w);
      d[8] = f2bf(f2.x);  d[9] = f2bf(f2.y);  d[10] = f2bf(f2.z); d[11] = f2bf(f2.w);
      d[12] = f2bf(f3.x); d[13] = f2bf(f3.y); d[14] = f2bf(f3.z); d[15] = f2bf(f3.w);
    }
    {
      int r = tid >> 3, cg = (tid & 7) * 8;
      size_t off = (size_t)(kk + r) * 256 + nc0 + cg;
      f32x4 g0, g1;
      if (nb < 4) {
        g0 = *(const f32x4*)(w1 + off);
        g1 = *(const f32x4*)(w1 + off + 4);
      } else if (nb < 8) {
        g0 = *(const f32x4*)(w2 + off);
        g1 = *(const f32x4*)(w2 + off + 4);
      } else {
        f32x4 a0 = *(const f32x4*)(w1 + off), a1 = *(const f32x4*)(w1 + off + 4);
        f32x4 b0 = *(const f32x4*)(w2 + off), b1 = *(const f32x4*)(w2 + off + 4);
        f32x4 d0 = *(const f32x4*)(w3 + off), d1 = *(const f32x4*)(w3 + off + 4);
        g0 = d0 - a0 - b0;
        g1 = d1 - a1 - b1;
      }
      tB[cg + 0][r] = f2bf(g0.x); tB[cg + 1][r] = f2bf(g0.y);
      tB[cg + 2][r] = f2bf(g0.z); tB[cg + 3][r] = f2bf(g0.w);
      tB[cg + 4][r] = f2bf(g1.x); tB[cg + 5][r] = f2bf(g1.y);
      tB[cg + 6][r] = f2bf(g1.z); tB[cg + 7][r] = f2bf(g1.w);
    }
    __syncthreads();
    FragAB af[4], bf[2];
#pragma unroll
    for (int mt = 0; mt < 4; mt++) {
      const unsigned short* p = &tA[wm * 64 + mt * 16 + l16][q * 8];
      af[mt].u[0] = *(const u16x4*)p;
      af[mt].u[1] = *(const u16x4*)(p + 4);
    }
#pragma unroll
    for (int nt = 0; nt < 2; nt++) {
      const unsigned short* p = &tB[wn * 32 + nt * 16 + l16][q * 8];
      bf[nt].u[0] = *(const u16x4*)p;
      bf[nt].u[1] = *(const u16x4*)(p + 4);
    }
#pragma unroll
    for (int mt = 0; mt < 4; mt++)
#pragma unroll
      for (int nt = 0; nt < 2; nt++)
        acc[mt][nt] = __builtin_amdgcn_mfma_f32_16x16x32_bf16(
            af[mt].f, bf[nt].f, acc[mt][nt], 0, 0, 0);
    __syncthreads();
  }
  int ty = nb >> 2;
#pragma unroll
  for (int mt = 0; mt < 4; mt++)
#pragma unroll
    for (int nt = 0; nt < 2; nt++) {
      int n = (nb & 3) * 64 + wn * 32 + nt * 16 + l16;
      int j0 = rb * 128 + wm * 64 + mt * 16 + q * 4;
      u16x4 hv;
      hv.x = f2bf(acc[mt][nt].x);
      hv.y = f2bf(acc[mt][nt].y);
      hv.z = f2bf(acc[mt][nt].z);
      hv.w = f2bf(acc[mt][nt].w);
      size_t idx = (size_t)ty * 2097152 + (size_t)(j0 >> 4) * 4096 + n * 16 + (j0 & 15);
      *(u16x4*)(Bp + idx) = hv;
    }
}

// ---------- kernel 2c: pack adj into pre-interleaved 2-bit planes ----------
// P word for (plane = (col32)*2+q, row): covers 16 elems (octets kh=0,1 of
// the q-half). Bit layout (kh adds +4 to every position):
//   bit( j+4kh)     = bit0 of elem 2j      bit(16+j+4kh) = bit0 of elem 2j+1
//   bit(8+j+4kh)    = bit1 of elem 2j      bit(24+j+4kh) = bit1 of elem 2j+1
// -> k_agg extracts frag dword j of plane A as (w>>(4kh+j))&0x10001 (pair of
//    u16 lanes!), then *0x3F80 gives bf16 one-hot. 3 VALU per plane-dword.
__global__ __launch_bounds__(256) void k_pack(const int* __restrict__ adj,
                                              unsigned* __restrict__ P) {
  int bx = blockIdx.x;
  int rowblk = bx >> 3, ks = bx & 7;
  int t = threadIdx.x;
  int r0 = rowblk * 32;
  __shared__ unsigned hal[32][129];  // per-octet sparse codes, padded

  int rl = t >> 7;  // 0/1
  int o = t & 127;
  const int* src0 = adj + (size_t)(r0 + rl) * NN + ks * 1024 + o * 8;
  i32x4 v0 = *(const i32x4*)src0;
  i32x4 v1 = *(const i32x4*)(src0 + 4);
  for (int p = 0; p < 16; p++) {
    i32x4 u0 = v0, u1 = v1;
    if (p < 15) {
      const int* s = src0 + (size_t)(p + 1) * 2 * NN;
      v0 = *(const i32x4*)s;
      v1 = *(const i32x4*)(s + 4);
    }
    int cs[8] = {u0.x, u0.y, u0.z, u0.w, u1.x, u1.y, u1.z, u1.w};
    unsigned code = 0;
#pragma unroll
    for (int j = 0; j < 4; j++) {
      code |= (unsigned)(cs[2 * j] & 1) << j;
      code |= (unsigned)((cs[2 * j] >> 1) & 1) << (8 + j);
      code |= (unsigned)(cs[2 * j + 1] & 1) << (16 + j);
      code |= (unsigned)((cs[2 * j + 1] >> 1) & 1) << (24 + j);
    }
    hal[p * 2 + rl][o] = code;
  }
  __syncthreads();
  // phase 2: 2048 u32 out; lanes sweep row -> 128B contiguous segments
  for (int i = 0; i < 8; i++) {
    int oi = i * 256 + t;
    int row = oi & 31, sq = oi >> 5;  // sq = s*2+q
    int s = sq >> 1, q = sq & 1;
    unsigned lo = hal[row][s * 4 + q];       // kh=0 octet
    unsigned hi = hal[row][s * 4 + 2 + q];   // kh=1 octet
    P[((size_t)(ks * 32 + s) * 2 + q) * 8192 + r0 + row] = lo | (hi << 4);
  }
}

// ---------- kernel 3: out += b0@H1 + b1@H2 + (b0&b1)@H12 ----------
// v8: BM=128, BN=128, BK=32, splitK=8 -> 1024 blocks, 3 resident/CU.
// 256 thr = 4 waves, wave grid 2m x 2n, wave tile 64x64 (acc = 64 AGPR).
// NO LDS / barriers. A-side: 2 coalesced u32 P loads/wave/step (prefetched);
// masks via 3-VALU-per-dword extraction (see k_pack layout). B direct from
// global (coalesced 1KB/wave, XCD-L2-resident via ks=bx&7).
__global__ __launch_bounds__(256, 3) void k_agg(const unsigned* __restrict__ P,
                                                const unsigned short* __restrict__ Bp,
                                                float* __restrict__ out) {
  int bx = blockIdx.x;
  int ks = bx & 7;
  int cb = (bx >> 3) & 1;   // 128-col half
  int rb = bx >> 4;         // 0..63, 128-row tile
  int tid = threadIdx.x, lane = tid & 63;
  int wv = tid >> 6;
  int wm = wv >> 1, wn = wv & 1;
  int q = lane >> 5, l32 = lane & 31;

  f32x16 acc[2][2];
  acc[0][0] = (f32x16)0.0f;
  acc[0][1] = (f32x16)0.0f;
  acc[1][0] = (f32x16)0.0f;
  acc[1][1] = (f32x16)0.0f;

  // packed-adj pointer: plane (ks*32+s)*2+q, row rb*128 + wm*64 + mt*32 + l32
  const unsigned* pp = P + ((size_t)ks * 64 + q) * 8192 + rb * 128 + wm * 64 + l32;

  // B pointers: n = cb*128 + wn*64 + nt*32 + l32; k-slice base ks*262144
  const unsigned short* bb[3][2];
#pragma unroll
  for (int ty = 0; ty < 3; ty++)
#pragma unroll
    for (int nt = 0; nt < 2; nt++) {
      int n = cb * 128 + wn * 64 + nt * 32 + l32;
      bb[ty][nt] = Bp + (size_t)ty * 2097152 + (size_t)ks * 262144 + n * 16 + q * 8;
    }

  unsigned pk[2], npk[2] = {0, 0};
  pk[0] = pp[0];
  pk[1] = pp[32];

  for (int s = 0; s < 32; s++) {
    // batch-issue 12 B loads (coalesced 1KB/wave, XCD-L2-resident)
    FragAB bv[2][3][2];
    size_t soff = (size_t)s * 8192;
#pragma unroll
    for (int kh = 0; kh < 2; kh++)
#pragma unroll
      for (int ty = 0; ty < 3; ty++)
#pragma unroll
        for (int nt = 0; nt < 2; nt++)
          bv[kh][ty][nt].v = *(const i32x4*)(bb[ty][nt] + soff + kh * 4096);
    // prefetch next step's packed adj (2 coalesced u32 loads)
    if (s < 31) {
      npk[0] = pp[(size_t)(s + 1) * 16384];
      npk[1] = pp[(size_t)(s + 1) * 16384 + 32];
    }
    // extract masks (3 VALU/plane-dword) + 24 MFMAs
#pragma unroll
    for (int mt = 0; mt < 2; mt++) {
      unsigned w = pk[mt];
#pragma unroll
      for (int kh = 0; kh < 2; kh++) {
        FragAB fA, fB, fC;
#pragma unroll
        for (int j = 0; j < 4; j++) {
          unsigned a = (w >> (4 * kh + j)) & 0x10001u;
          unsigned b = (w >> (4 * kh + j + 8)) & 0x10001u;
          unsigned fa = a * 0x3F80u;  // u24 mul -> bf16 1.0 in each u16 lane
          unsigned fb = b * 0x3F80u;
          fA.v[j] = (int)fa;
          fB.v[j] = (int)fb;
          fC.v[j] = (int)(fa & fb);
        }
        acc[mt][0] = __builtin_amdgcn_mfma_f32_32x32x16_bf16(
            fA.f, bv[kh][0][0].f, acc[mt][0], 0, 0, 0);
        acc[mt][1] = __builtin_amdgcn_mfma_f32_32x32x16_bf16(
            fA.f, bv[kh][0][1].f, acc[mt][1], 0, 0, 0);
        acc[mt][0] = __builtin_amdgcn_mfma_f32_32x32x16_bf16(
            fB.f, bv[kh][1][0].f, acc[mt][0], 0, 0, 0);
        acc[mt][1] = __builtin_amdgcn_mfma_f32_32x32x16_bf16(
            fB.f, bv[kh][1][1].f, acc[mt][1], 0, 0, 0);
        acc[mt][0] = __builtin_amdgcn_mfma_f32_32x32x16_bf16(
            fC.f, bv[kh][2][0].f, acc[mt][0], 0, 0, 0);
        acc[mt][1] = __builtin_amdgcn_mfma_f32_32x32x16_bf16(
            fC.f, bv[kh][2][1].f, acc[mt][1], 0, 0, 0);
      }
    }
    pk[0] = npk[0];
    pk[1] = npk[1];
  }

  // epilogue: C/D 32x32 layout col=lane&31, row=(reg&3)+8*(reg>>2)+4*q
#pragma unroll
  for (int mt = 0; mt < 2; mt++)
#pragma unroll
    for (int nt = 0; nt < 2; nt++) {
      int colbase = cb * 128 + wn * 64 + nt * 32 + l32;
      int rowb = rb * 128 + wm * 64 + mt * 32 + 4 * q;
#pragma unroll
      for (int r = 0; r < 16; r++) {
        int row = rowb + (r & 3) + 8 * (r >> 2);
        atomicAdd(out + (size_t)row * 256 + colbase, acc[mt][nt][r]);
      }
    }
}

extern "C" void kernel_launch(void* const* d_in, const int* in_sizes, int n_in,
                              void* d_out, int out_size, void* d_ws,
                              size_t ws_size, hipStream_t stream) {
  const float* V = (const float*)d_in[0];
  const int* adj = (const int*)d_in[1];
  const float* w1 = (const float*)d_in[2];
  const float* w2 = (const float*)d_in[3];
  const float* w3 = (const float*)d_in[4];
  const float* bias = (const float*)d_in[5];
  float* out = (float*)d_out;
  unsigned short* Bp = (unsigned short*)d_ws;            // 12.58 MB
  unsigned* P = (unsigned*)((char*)d_ws + 12582912);     // +16.78 MB

  k_bias<<<dim3(NN), dim3(256), 0, stream>>>(bias, out);
  k_pack<<<dim3(2048), dim3(256), 0, stream>>>(adj, P);
  k_transform<<<dim3(768), dim3(256), 0, stream>>>(V, w1, w2, w3, Bp);
  k_agg<<<dim3(1024), dim3(256), 0, stream>>>(P, Bp, out);
}